// Round 3
// baseline (1090.578 us; speedup 1.0000x reference)
//
#include <hip/hip_runtime.h>

// R6: LDS-issue pressure reduction (weight-read amortization).
// R5 post-mortem: WRITE collapsed (localMem theory confirmed), now VALUBusy
// 53%, HBM 3%. Instruction-mix arithmetic shows wave-uniform weight
// ds_read_b128s are re-issued per output position: stage 3 = 288 LD4 vs 1152
// FMA per pos. R6 pairs outputs per thread so every weight load feeds 2
// outputs (identical per-accumulator FMA order -> bitwise-identical result):
//   stage 2: 400 thr x 2 adjacent pool outputs (1x4 conv strip per half)
//   stage 3: 400 thr x 2 adjacent cols, shared taps
//   stage 4/5: each lane does pos=lane and pos=lane+64 in one body
// LDS map, numerics, launch config unchanged from R5.

#define NT 512

// ---- LDS byte offsets ----
#define O_XS    0        // [6][102][34] bf16 = 41616
#define O_H2S   0        // [16][800]    bf16 = 25600  (xs dead)
#define O_H3S   25600    // [32][80]     bf16 = 5120   -> 30720
#define O_P1S   41616    // [8][52][18]  bf16 = 14976  -> 56592
#define O_P2S   56592    // [16][12][10] bf16 = 3840   -> 60432
#define O_FV    60432    // [256] f32    = 1024        -> 61456
#define O_W1T   61456    // [54][8]   1728 -> 63184   (stage 2)
#define O_B1    63184    //   32 -> 63216
#define O_WP1T  63216    // [4][8][8] 1024 -> 64240
#define O_BP1   64240    //   32 -> 64272
#define O_W2T   25600    // [72][16]  4608 -> 30208   (stage 3)
#define O_B2    30208    //   64 -> 30272
#define O_WP2   41616    // [16][160] 10240 -> 51856  (stage 4)
#define O_BP2   51856    //   64 -> 51920
#define O_W3T   0        // [144][32] 18432 -> 18432  (stage 5)
#define O_B3    18432    //  128 -> 18560
#define O_WP3A  0        // oc 0..15, row stride 324: 20736       (stage 6)
#define O_BP3   20736    //  128 -> 20864
#define O_WP3B  30720    // oc 16..31: 20736 -> 51456
#define O_WMU   0        // [7][256] 7168            (stage 7)
#define O_WLV   7168     // 7168 -> 14336
#define O_BMU   14336    //   28
#define O_BLV   14368    //   28 -> 14396

#define SMEM_BYTES 64288

typedef float f32x8  __attribute__((ext_vector_type(8)));
typedef float f32x16 __attribute__((ext_vector_type(16)));

__device__ __forceinline__ float bf2f(unsigned short u) {
    union { unsigned int i; float f; } v; v.i = ((unsigned int)u) << 16; return v.f;
}
__device__ __forceinline__ float bflo(unsigned int u) {
    union { unsigned int i; float f; } v; v.i = u << 16; return v.f;
}
__device__ __forceinline__ float bfhi(unsigned int u) {
    union { unsigned int i; float f; } v; v.i = u & 0xffff0000u; return v.f;
}
__device__ __forceinline__ unsigned short f2bf(float f) {
    union { float f; unsigned int i; } v; v.f = f;
    unsigned int r = v.i + 0x7FFF + ((v.i >> 16) & 1);   // RNE
    return (unsigned short)(r >> 16);
}
__device__ __forceinline__ float lrelu(float v) { return fmaxf(v, 0.01f * v); }

#define LD4(p) (*(const float4*)(p))

__device__ __forceinline__ void fma8v(f32x8& a, const float4& wA, const float4& wB, float x) {
    a[0] = __builtin_fmaf(wA.x, x, a[0]); a[1] = __builtin_fmaf(wA.y, x, a[1]);
    a[2] = __builtin_fmaf(wA.z, x, a[2]); a[3] = __builtin_fmaf(wA.w, x, a[3]);
    a[4] = __builtin_fmaf(wB.x, x, a[4]); a[5] = __builtin_fmaf(wB.y, x, a[5]);
    a[6] = __builtin_fmaf(wB.z, x, a[6]); a[7] = __builtin_fmaf(wB.w, x, a[7]);
}
__device__ __forceinline__ void fma16v(f32x16& a, const float4& w0, const float4& w1,
                                       const float4& w2, const float4& w3, float x) {
    a[0]  = __builtin_fmaf(w0.x, x, a[0]);  a[1]  = __builtin_fmaf(w0.y, x, a[1]);
    a[2]  = __builtin_fmaf(w0.z, x, a[2]);  a[3]  = __builtin_fmaf(w0.w, x, a[3]);
    a[4]  = __builtin_fmaf(w1.x, x, a[4]);  a[5]  = __builtin_fmaf(w1.y, x, a[5]);
    a[6]  = __builtin_fmaf(w1.z, x, a[6]);  a[7]  = __builtin_fmaf(w1.w, x, a[7]);
    a[8]  = __builtin_fmaf(w2.x, x, a[8]);  a[9]  = __builtin_fmaf(w2.y, x, a[9]);
    a[10] = __builtin_fmaf(w2.z, x, a[10]); a[11] = __builtin_fmaf(w2.w, x, a[11]);
    a[12] = __builtin_fmaf(w3.x, x, a[12]); a[13] = __builtin_fmaf(w3.y, x, a[13]);
    a[14] = __builtin_fmaf(w3.z, x, a[14]); a[15] = __builtin_fmaf(w3.w, x, a[15]);
}

extern "C" __global__ void __launch_bounds__(512, 4)
vae_encoder_kernel(const float* __restrict__ x,
                   const float* __restrict__ w1,  const float* __restrict__ b1,
                   const float* __restrict__ w2,  const float* __restrict__ b2,
                   const float* __restrict__ w3,  const float* __restrict__ b3,
                   const float* __restrict__ wp1, const float* __restrict__ bp1,
                   const float* __restrict__ wp2, const float* __restrict__ bp2,
                   const float* __restrict__ wp3, const float* __restrict__ bp3,
                   const float* __restrict__ wmu, const float* __restrict__ bmu,
                   const float* __restrict__ wlv, const float* __restrict__ blv,
                   float* __restrict__ out)
{
    __shared__ __align__(16) unsigned char smem[SMEM_BYTES];
    unsigned short* xs  = (unsigned short*)(smem + O_XS);
    unsigned short* h2s = (unsigned short*)(smem + O_H2S);
    unsigned short* h3s = (unsigned short*)(smem + O_H3S);
    unsigned short* p1s = (unsigned short*)(smem + O_P1S);
    unsigned short* p2s = (unsigned short*)(smem + O_P2S);
    float*          fv  = (float*)(smem + O_FV);

    const int tid  = threadIdx.x;
    const int b    = blockIdx.x;
    const int lane = tid & 63;
    const int wave = tid >> 6;

    // ---- 0) zero activation LDS (halo borders must be 0) ----
    for (int i = tid; i < 3841; i += NT)           // 3841*16 = 61456
        ((int4*)smem)[i] = int4{0, 0, 0, 0};
    __syncthreads();

    // ---- 1) load x -> xs (bf16, +1 halo)  +  copy stage-2 weights ----
    {
        const float* xb = x + (size_t)b * 19200;
        for (int i = tid; i < 4800; i += NT) {
            float4 v = ((const float4*)xb)[i];
            int c   = i / 800;
            int rem = i - c * 800;
            int row = rem >> 3;
            int c4  = rem & 7;
            int base = c * 3468 + (row + 1) * 34 + (c4 * 4 + 1);
            xs[base + 0] = f2bf(v.x); xs[base + 1] = f2bf(v.y);
            xs[base + 2] = f2bf(v.z); xs[base + 3] = f2bf(v.w);
        }
        float* w1t  = (float*)(smem + O_W1T);
        float* b1s  = (float*)(smem + O_B1);
        float* wp1t = (float*)(smem + O_WP1T);
        float* bp1s = (float*)(smem + O_BP1);
        for (int i = tid; i < 432; i += NT) {      // w1t[r][o] = w1[o][r]
            int o = i & 7, r = i >> 3;
            w1t[i] = w1[o * 54 + r];
        }
        for (int i = tid; i < 256; i += NT) {      // wp1t[k][ic][o] = wp1[o][ic][k]
            int o = i & 7, ic = (i >> 3) & 7, k = i >> 6;
            wp1t[i] = wp1[(o * 8 + ic) * 4 + k];
        }
        if (tid < 8)  b1s[tid]  = b1[tid];
        if (tid < 8)  bp1s[tid] = bp1[tid];
    }
    __syncthreads();

    // ---- 2) conv1(3x3,6->8)+lrelu fused with pool1(2x2/2,8->8) -> p1s ----
    // 400 threads, each: 2 adjacent pool outputs = 2x4 conv strip (1x4/half).
    // Weight loads shared across all 4 conv columns; per-acc FMA order == R5.
    {
        const float* w1s  = (const float*)(smem + O_W1T);
        const float* b1s  = (const float*)(smem + O_B1);
        const float* wp1s = (const float*)(smem + O_WP1T);
        const float* bp1s = (const float*)(smem + O_BP1);

#define S2ROW(i) do {                                                          \
    const unsigned short* rp_ = rb + (i) * 34;                                 \
    unsigned int u0_ = *(const unsigned int*)(rp_ + 0);                        \
    unsigned int u1_ = *(const unsigned int*)(rp_ + 2);                        \
    unsigned int u2_ = *(const unsigned int*)(rp_ + 4);                        \
    float x0_ = bflo(u0_), x1_ = bfhi(u0_), x2_ = bflo(u1_);                   \
    float x3_ = bfhi(u1_), x4_ = bflo(u2_), x5_ = bfhi(u2_);                   \
    const float* wr_ = &w1s[(c * 9 + (i) * 3) * 8];                            \
    { float4 wA_ = LD4(wr_ + 0),  wB_ = LD4(wr_ + 4);                          \
      fma8v(h0, wA_, wB_, x0_); fma8v(h1, wA_, wB_, x1_);                      \
      fma8v(h2, wA_, wB_, x2_); fma8v(h3, wA_, wB_, x3_); }                    \
    { float4 wA_ = LD4(wr_ + 8),  wB_ = LD4(wr_ + 12);                         \
      fma8v(h0, wA_, wB_, x1_); fma8v(h1, wA_, wB_, x2_);                      \
      fma8v(h2, wA_, wB_, x3_); fma8v(h3, wA_, wB_, x4_); }                    \
    { float4 wA_ = LD4(wr_ + 16), wB_ = LD4(wr_ + 20);                         \
      fma8v(h0, wA_, wB_, x2_); fma8v(h1, wA_, wB_, x3_);                      \
      fma8v(h2, wA_, wB_, x4_); fma8v(h3, wA_, wB_, x5_); }                    \
} while (0)

#define POOLP(ic) do {                                                         \
    float vA0_ = lrelu(h0[ic]), vA1_ = lrelu(h1[ic]);                          \
    float vB0_ = lrelu(h2[ic]), vB1_ = lrelu(h3[ic]);                          \
    const float* g0_ = &wp1s[(k0 * 8 + (ic)) * 8];                             \
    const float* g1_ = &wp1s[(k1 * 8 + (ic)) * 8];                             \
    float4 g0a_ = LD4(g0_), g0b_ = LD4(g0_ + 4);                               \
    float4 g1a_ = LD4(g1_), g1b_ = LD4(g1_ + 4);                               \
    fma8v(accA, g0a_, g0b_, vA0_); fma8v(accA, g1a_, g1b_, vA1_);              \
    fma8v(accB, g0a_, g0b_, vB0_); fma8v(accB, g1a_, g1b_, vB1_);              \
} while (0)

        if (tid < 400) {
            const int pr  = tid >> 3;       // 0..49
            const int q   = tid & 7;        // 0..7
            const int cc0 = q << 2;         // conv/padded col base (0..28)
            const int pc0 = q << 1;         // pool col base (0..14)
            f32x8 accA, accB;
            {
                float4 bA = LD4(&bp1s[0]);
                float4 bB = LD4(&bp1s[4]);
                accA[0]=bA.x; accA[1]=bA.y; accA[2]=bA.z; accA[3]=bA.w;
                accA[4]=bB.x; accA[5]=bB.y; accA[6]=bB.z; accA[7]=bB.w;
                accB = accA;
            }
            #pragma unroll
            for (int h = 0; h < 2; h++) {
                const int k0 = 2 * h, k1 = 2 * h + 1;
                f32x8 h0, h1, h2, h3;
                {
                    float4 bA = LD4(&b1s[0]);
                    float4 bB = LD4(&b1s[4]);
                    h0[0]=bA.x; h0[1]=bA.y; h0[2]=bA.z; h0[3]=bA.w;
                    h0[4]=bB.x; h0[5]=bB.y; h0[6]=bB.z; h0[7]=bB.w;
                    h1 = h0; h2 = h0; h3 = h0;
                }
                #pragma unroll 1
                for (int c = 0; c < 6; c++) {
                    const unsigned short* rb =
                        &xs[c * 3468 + (2 * pr + h) * 34 + cc0];
                    S2ROW(0); S2ROW(1); S2ROW(2);
                }
                POOLP(0); POOLP(1); POOLP(2); POOLP(3);
                POOLP(4); POOLP(5); POOLP(6); POOLP(7);
            }
            {
                const int pb = (pr + 1) * 18 + (pc0 + 1);
                p1s[0 * 936 + pb] = f2bf(accA[0]); p1s[0 * 936 + pb + 1] = f2bf(accB[0]);
                p1s[1 * 936 + pb] = f2bf(accA[1]); p1s[1 * 936 + pb + 1] = f2bf(accB[1]);
                p1s[2 * 936 + pb] = f2bf(accA[2]); p1s[2 * 936 + pb + 1] = f2bf(accB[2]);
                p1s[3 * 936 + pb] = f2bf(accA[3]); p1s[3 * 936 + pb + 1] = f2bf(accB[3]);
                p1s[4 * 936 + pb] = f2bf(accA[4]); p1s[4 * 936 + pb + 1] = f2bf(accB[4]);
                p1s[5 * 936 + pb] = f2bf(accA[5]); p1s[5 * 936 + pb + 1] = f2bf(accB[5]);
                p1s[6 * 936 + pb] = f2bf(accA[6]); p1s[6 * 936 + pb + 1] = f2bf(accB[6]);
                p1s[7 * 936 + pb] = f2bf(accA[7]); p1s[7 * 936 + pb + 1] = f2bf(accB[7]);
            }
        }
#undef S2ROW
#undef POOLP
    }
    __syncthreads();

    // ---- copy stage-3 weights (w2 transposed) ----
    {
        float* w2t = (float*)(smem + O_W2T);
        float* b2s = (float*)(smem + O_B2);
        for (int i = tid; i < 1152; i += NT) {     // w2t[r][o] = w2[o][r]
            int o = i & 15, r = i >> 4;
            w2t[i] = w2[o * 72 + r];
        }
        if (tid < 16) b2s[tid] = b2[tid];
    }
    __syncthreads();

    // ---- 3) conv2(3x3,8->16)+lrelu -> h2s ----
    // 400 threads x 2 adjacent output cols; 36 weight LD4/ic shared by both.
    {
        const float* w2s = (const float*)(smem + O_W2T);
        const float* b2s = (const float*)(smem + O_B2);

#define S3TAP(dy, dx, xa, xb) do {                                             \
    const float* wg_ = &w2s[(icv * 9 + (dy) * 3 + (dx)) * 16];                 \
    float4 w0_ = LD4(wg_), w1_ = LD4(wg_ + 4);                                 \
    float4 w2_ = LD4(wg_ + 8), w3_ = LD4(wg_ + 12);                            \
    fma16v(accA, w0_, w1_, w2_, w3_, (xa));                                    \
    fma16v(accB, w0_, w1_, w2_, w3_, (xb));                                    \
} while (0)

#define S3DY(dy) do {                                                          \
    const unsigned short* rp_ = rb + (dy) * 18;                                \
    unsigned int u0_ = *(const unsigned int*)(rp_);                            \
    unsigned int u1_ = *(const unsigned int*)(rp_ + 2);                        \
    float x0_ = bflo(u0_), x1_ = bfhi(u0_);                                    \
    float x2_ = bflo(u1_), x3_ = bfhi(u1_);                                    \
    S3TAP(dy, 0, x0_, x1_); S3TAP(dy, 1, x1_, x2_); S3TAP(dy, 2, x2_, x3_);    \
} while (0)

#define H2ST(o) do {                                                           \
    h2s[(o) * 800 + posA] = f2bf(lrelu(accA[o]));                              \
    h2s[(o) * 800 + posA + 1] = f2bf(lrelu(accB[o]));                          \
} while (0)

        if (tid < 400) {
            const int r  = tid >> 3;        // 0..49
            const int c0 = (tid & 7) << 1;  // 0..14 (even)
            f32x16 accA, accB;
            {
                float4 b0 = LD4(&b2s[0]);
                float4 b1v = LD4(&b2s[4]);
                float4 b2v = LD4(&b2s[8]);
                float4 b3v = LD4(&b2s[12]);
                accA[0]=b0.x;  accA[1]=b0.y;  accA[2]=b0.z;  accA[3]=b0.w;
                accA[4]=b1v.x; accA[5]=b1v.y; accA[6]=b1v.z; accA[7]=b1v.w;
                accA[8]=b2v.x; accA[9]=b2v.y; accA[10]=b2v.z; accA[11]=b2v.w;
                accA[12]=b3v.x; accA[13]=b3v.y; accA[14]=b3v.z; accA[15]=b3v.w;
                accB = accA;
            }
            #pragma unroll 1
            for (int icv = 0; icv < 8; icv++) {
                const unsigned short* rb = &p1s[icv * 936 + r * 18 + c0];
                S3DY(0); S3DY(1); S3DY(2);
            }
            const int posA = r * 16 + c0;
            H2ST(0);  H2ST(1);  H2ST(2);  H2ST(3);
            H2ST(4);  H2ST(5);  H2ST(6);  H2ST(7);
            H2ST(8);  H2ST(9);  H2ST(10); H2ST(11);
            H2ST(12); H2ST(13); H2ST(14); H2ST(15);
        }
#undef S3TAP
#undef S3DY
#undef H2ST
    }
    __syncthreads();

    // ---- copy stage-4 weights (wp2 plain) ----
    {
        float* wp2s = (float*)(smem + O_WP2);
        float* bp2s = (float*)(smem + O_BP2);
        for (int i = tid; i < 2560; i += NT) wp2s[i] = wp2[i];
        if (tid < 16) bp2s[tid] = bp2[tid];
    }
    __syncthreads();

    // ---- 4) pool2 (5x2 / (5,2), 16->16) -> p2s ----
    // Each lane computes pos=lane and pos=lane+64 in one body: weight reads
    // (wave-uniform) issued once for both.
    {
        const float* wp2s = (const float*)(smem + O_WP2);
        const float* bp2s = (const float*)(smem + O_BP2);
        const int oc0 = wave;                       // 0..7, handles oc0 & oc0+8

#define T4P(k, xa, xb) do {                                                    \
    float w0_ = wr0[k], w1_ = wr1[k];                                          \
    float xa_ = (xa), xb_ = (xb);                                              \
    a0 = __builtin_fmaf(w0_, xa_, a0);                                         \
    a1 = __builtin_fmaf(w1_, xa_, a1);                                         \
    a2 = __builtin_fmaf(w0_, xb_, a2);                                         \
    a3 = __builtin_fmaf(w1_, xb_, a3);                                         \
} while (0)

        {
            const int posA = lane;
            const int sB   = (lane < 16);
            const int posB = sB ? lane + 64 : lane;
            const int prA = posA >> 3, pcA = posA & 7;
            const int prB = posB >> 3, pcB = posB & 7;
            float a0 = bp2s[oc0], a1 = bp2s[oc0 + 8];
            float a2 = a0, a3 = a1;
            #pragma unroll 1
            for (int ic = 0; ic < 16; ic++) {
                const unsigned short* hA = &h2s[ic * 800 + 5 * prA * 16 + 2 * pcA];
                const unsigned short* hB = &h2s[ic * 800 + 5 * prB * 16 + 2 * pcB];
                unsigned int uA0 = *(const unsigned int*)(hA + 0);
                unsigned int uA1 = *(const unsigned int*)(hA + 16);
                unsigned int uA2 = *(const unsigned int*)(hA + 32);
                unsigned int uA3 = *(const unsigned int*)(hA + 48);
                unsigned int uA4 = *(const unsigned int*)(hA + 64);
                unsigned int uB0 = *(const unsigned int*)(hB + 0);
                unsigned int uB1 = *(const unsigned int*)(hB + 16);
                unsigned int uB2 = *(const unsigned int*)(hB + 32);
                unsigned int uB3 = *(const unsigned int*)(hB + 48);
                unsigned int uB4 = *(const unsigned int*)(hB + 64);
                const float* wr0 = &wp2s[oc0 * 160 + ic * 10];
                const float* wr1 = &wp2s[(oc0 + 8) * 160 + ic * 10];
                T4P(0, bflo(uA0), bflo(uB0)); T4P(1, bfhi(uA0), bfhi(uB0));
                T4P(2, bflo(uA1), bflo(uB1)); T4P(3, bfhi(uA1), bfhi(uB1));
                T4P(4, bflo(uA2), bflo(uB2)); T4P(5, bfhi(uA2), bfhi(uB2));
                T4P(6, bflo(uA3), bflo(uB3)); T4P(7, bfhi(uA3), bfhi(uB3));
                T4P(8, bflo(uA4), bflo(uB4)); T4P(9, bfhi(uA4), bfhi(uB4));
            }
            p2s[oc0 * 120 + (prA + 1) * 10 + (pcA + 1)]       = f2bf(a0);
            p2s[(oc0 + 8) * 120 + (prA + 1) * 10 + (pcA + 1)] = f2bf(a1);
            if (sB) {
                p2s[oc0 * 120 + (prB + 1) * 10 + (pcB + 1)]       = f2bf(a2);
                p2s[(oc0 + 8) * 120 + (prB + 1) * 10 + (pcB + 1)] = f2bf(a3);
            }
        }
#undef T4P
    }
    __syncthreads();

    // ---- copy stage-5 weights (w3 transposed) ----
    {
        float* w3t = (float*)(smem + O_W3T);
        float* b3s = (float*)(smem + O_B3);
        for (int i = tid; i < 4608; i += NT) {     // w3t[r][o] = w3[o][r]
            int o = i & 31, r = i >> 5;
            w3t[i] = w3[o * 144 + r];
        }
        if (tid < 32) b3s[tid] = b3[tid];
    }
    __syncthreads();

    // ---- 5) conv3(3x3,16->32)+lrelu -> h3s ----
    // Each lane computes pos=lane and pos=lane+64; 9 weight LD4/ic shared.
    {
        const float* w3s = (const float*)(smem + O_W3T);
        const float* b3s = (const float*)(smem + O_B3);
        const int ocg = wave;                       // 4 oc per wave

#define T5P(k, xa, xb) do {                                                    \
    float4 w_ = LD4(wg + (k) * 32);                                            \
    float xa_ = (xa), xb_ = (xb);                                              \
    a0 = __builtin_fmaf(w_.x, xa_, a0);                                        \
    a1 = __builtin_fmaf(w_.y, xa_, a1);                                        \
    a2 = __builtin_fmaf(w_.z, xa_, a2);                                        \
    a3 = __builtin_fmaf(w_.w, xa_, a3);                                        \
    a4 = __builtin_fmaf(w_.x, xb_, a4);                                        \
    a5 = __builtin_fmaf(w_.y, xb_, a5);                                        \
    a6 = __builtin_fmaf(w_.z, xb_, a6);                                        \
    a7 = __builtin_fmaf(w_.w, xb_, a7);                                        \
} while (0)

        {
            const int posA = lane;
            const int sB   = (lane < 16);
            const int posB = sB ? lane + 64 : lane;
            const int rA = posA >> 3, cA = posA & 7;
            const int rB = posB >> 3, cB = posB & 7;
            float4 bv = LD4(&b3s[ocg * 4]);
            float a0 = bv.x, a1 = bv.y, a2 = bv.z, a3 = bv.w;
            float a4 = bv.x, a5 = bv.y, a6 = bv.z, a7 = bv.w;
            #pragma unroll 1
            for (int ic = 0; ic < 16; ic++) {
                const unsigned short* rbA = &p2s[ic * 120 + rA * 10 + cA];
                const unsigned short* rbB = &p2s[ic * 120 + rB * 10 + cB];
                float xA0 = bf2f(rbA[0]),  xA1 = bf2f(rbA[1]),  xA2 = bf2f(rbA[2]);
                float xA3 = bf2f(rbA[10]), xA4 = bf2f(rbA[11]), xA5 = bf2f(rbA[12]);
                float xA6 = bf2f(rbA[20]), xA7 = bf2f(rbA[21]), xA8 = bf2f(rbA[22]);
                float xB0 = bf2f(rbB[0]),  xB1 = bf2f(rbB[1]),  xB2 = bf2f(rbB[2]);
                float xB3 = bf2f(rbB[10]), xB4 = bf2f(rbB[11]), xB5 = bf2f(rbB[12]);
                float xB6 = bf2f(rbB[20]), xB7 = bf2f(rbB[21]), xB8 = bf2f(rbB[22]);
                const float* wg = &w3s[ic * 288 + ocg * 4];
                T5P(0, xA0, xB0); T5P(1, xA1, xB1); T5P(2, xA2, xB2);
                T5P(3, xA3, xB3); T5P(4, xA4, xB4); T5P(5, xA5, xB5);
                T5P(6, xA6, xB6); T5P(7, xA7, xB7); T5P(8, xA8, xB8);
            }
            h3s[(ocg*4+0)*80 + posA] = f2bf(lrelu(a0));
            h3s[(ocg*4+1)*80 + posA] = f2bf(lrelu(a1));
            h3s[(ocg*4+2)*80 + posA] = f2bf(lrelu(a2));
            h3s[(ocg*4+3)*80 + posA] = f2bf(lrelu(a3));
            if (sB) {
                h3s[(ocg*4+0)*80 + posB] = f2bf(lrelu(a4));
                h3s[(ocg*4+1)*80 + posB] = f2bf(lrelu(a5));
                h3s[(ocg*4+2)*80 + posB] = f2bf(lrelu(a6));
                h3s[(ocg*4+3)*80 + posB] = f2bf(lrelu(a7));
            }
        }
#undef T5P
    }
    __syncthreads();

    // ---- copy stage-6 weights (wp3, row stride 324 to spread banks) ----
    {
        float* wA = (float*)(smem + O_WP3A);
        float* wB = (float*)(smem + O_WP3B);
        float* bp3s = (float*)(smem + O_BP3);
        for (int oc = wave; oc < 32; oc += 8) {
            float* dst = (oc < 16) ? (wA + oc * 324) : (wB + (oc - 16) * 324);
            const float* src = wp3 + oc * 320;
            for (int j = lane; j < 320; j += 64) dst[j] = src[j];
        }
        if (tid < 32) bp3s[tid] = bp3[tid];
    }
    __syncthreads();

    // ---- 6) pool3 (5x2 / (5,2), 32->32) -> fv[256] ----
    {
        const float* bp3s = (const float*)(smem + O_BP3);

#define T6(k, xv) a = __builtin_fmaf(wrow[ic * 10 + (k)], (xv), a)

        if (tid < 256) {
            const int oc = tid >> 3, pos = tid & 7;
            const int pr = pos >> 2, pc = pos & 3;
            const float* wrow = (oc < 16)
                ? (const float*)(smem + O_WP3A) + oc * 324
                : (const float*)(smem + O_WP3B) + (oc - 16) * 324;
            float a = bp3s[oc];
            #pragma unroll 1
            for (int ic = 0; ic < 32; ic++) {
                const unsigned short* hb = &h3s[ic * 80 + 5 * pr * 8 + 2 * pc];
                unsigned int u0 = *(const unsigned int*)(hb + 0);
                unsigned int u1 = *(const unsigned int*)(hb + 8);
                unsigned int u2 = *(const unsigned int*)(hb + 16);
                unsigned int u3 = *(const unsigned int*)(hb + 24);
                unsigned int u4 = *(const unsigned int*)(hb + 32);
                T6(0, bflo(u0)); T6(1, bfhi(u0));
                T6(2, bflo(u1)); T6(3, bfhi(u1));
                T6(4, bflo(u2)); T6(5, bfhi(u2));
                T6(6, bflo(u3)); T6(7, bfhi(u3));
                T6(8, bflo(u4)); T6(9, bfhi(u4));
            }
            fv[oc * 8 + pos] = a;                   // flatten [32][2][4]
        }
#undef T6
    }
    __syncthreads();

    // ---- copy stage-7 weights ----
    {
        float* wmus = (float*)(smem + O_WMU);
        float* wlvs = (float*)(smem + O_WLV);
        float* bmus = (float*)(smem + O_BMU);
        float* blvs = (float*)(smem + O_BLV);
        for (int i = tid; i < 1792; i += NT) wmus[i] = wmu[i];
        for (int i = tid; i < 1792; i += NT) wlvs[i] = wlv[i];
        if (tid < 7) bmus[tid] = bmu[tid];
        if (tid < 7) blvs[tid] = blv[tid];
    }
    __syncthreads();

    // ---- 7) heads ----
    {
        const float* wmus = (const float*)(smem + O_WMU);
        const float* wlvs = (const float*)(smem + O_WLV);
        const float* bmus = (const float*)(smem + O_BMU);
        const float* blvs = (const float*)(smem + O_BLV);
        if (wave < 7) {
            const int j = wave;
            #pragma unroll
            for (int head = 0; head < 2; head++) {
                const float* W = head ? wlvs : wmus;
                float s = 0.f;
                #pragma unroll
                for (int q = 0; q < 4; q++) {
                    int k = lane + 64 * q;
                    s = __builtin_fmaf(fv[k], W[j * 256 + k], s);
                }
                #pragma unroll
                for (int m = 1; m < 64; m <<= 1) s += __shfl_xor(s, m);
                if (lane == 0) {
                    float r = s + (head ? blvs[j] : bmus[j]);
                    if (head) r = fminf(fmaxf(r, -5.f), 0.f);
                    out[head * 28672 + b * 7 + j] = r;
                }
            }
        }
    }
}

extern "C" void kernel_launch(void* const* d_in, const int* in_sizes, int n_in,
                              void* d_out, int out_size, void* d_ws, size_t ws_size,
                              hipStream_t stream) {
    const float* x   = (const float*)d_in[0];
    const float* w1  = (const float*)d_in[1];
    const float* b1  = (const float*)d_in[2];
    const float* w2  = (const float*)d_in[3];
    const float* b2  = (const float*)d_in[4];
    const float* w3  = (const float*)d_in[5];
    const float* b3  = (const float*)d_in[6];
    const float* wp1 = (const float*)d_in[7];
    const float* bp1 = (const float*)d_in[8];
    const float* wp2 = (const float*)d_in[9];
    const float* bp2 = (const float*)d_in[10];
    const float* wp3 = (const float*)d_in[11];
    const float* bp3 = (const float*)d_in[12];
    const float* wmu = (const float*)d_in[13];
    const float* bmu = (const float*)d_in[14];
    const float* wlv = (const float*)d_in[15];
    const float* blv = (const float*)d_in[16];
    float* out = (float*)d_out;

    hipLaunchKernelGGL(vae_encoder_kernel, dim3(4096), dim3(512), 0, stream,
                       x, w1, b1, w2, b2, w3, b3, wp1, bp1, wp2, bp2, wp3, bp3,
                       wmu, bmu, wlv, blv, out);
}